// Round 3
// baseline (6343.791 us; speedup 1.0000x reference)
//
#include <hip/hip_runtime.h>
#include <hip/hip_bf16.h>

#define BB 512
#define SS 17
#define VV 40002
#define VPAD 40064
#define EE 1024
#define HH 16
#define LL 12
#define FF 4096
#define DHD 64
#define NRELC 500
#define MTOK (BB*SS)            // 8704 tokens
#define BIGC 1000000.0f

typedef __bf16 bf16_t;
typedef __bf16 bf16x8 __attribute__((ext_vector_type(8)));
typedef __bf16 bf16x4 __attribute__((ext_vector_type(4)));
typedef float  f32x4  __attribute__((ext_vector_type(4)));

#define GLOAD_LDS16(g, l) __builtin_amdgcn_global_load_lds( \
    (const __attribute__((address_space(1))) void*)(g), \
    (__attribute__((address_space(3))) void*)(l), 16, 0, 0)

__device__ __forceinline__ float dgelu(float x) {
    return 0.5f * x * (1.f + erff(x * 0.70710678118654752f));
}
// tanh-based gelu (max abs err ~1e-3 vs exact — below bf16 output rounding)
__device__ __forceinline__ float fgelu(float x) {
    float y = 0.7978845608f * (x + 0.044715f * x * x * x);
    float u = __expf(2.f * y);
    float t = 1.f - 2.f / (u + 1.f);
    return 0.5f * x * (1.f + t);
}

// ---------------- block reductions (256 threads = 4 waves) ----------------
__device__ __forceinline__ float blk_sum(float v, float* sred) {
#pragma unroll
    for (int o = 32; o > 0; o >>= 1) v += __shfl_down(v, o);
    int lane = threadIdx.x & 63, w = threadIdx.x >> 6;
    __syncthreads();
    if (lane == 0) sred[w] = v;
    __syncthreads();
    return sred[0] + sred[1] + sred[2] + sred[3];
}
__device__ __forceinline__ float blk_max(float v, float* sred) {
#pragma unroll
    for (int o = 32; o > 0; o >>= 1) v = fmaxf(v, __shfl_down(v, o));
    int lane = threadIdx.x & 63, w = threadIdx.x >> 6;
    __syncthreads();
    if (lane == 0) sred[w] = v;
    __syncthreads();
    return fmaxf(fmaxf(sred[0], sred[1]), fmaxf(sred[2], sred[3]));
}

// ---------------- edge tables ----------------------------------------------
__global__ __launch_bounds__(256)
void edge_kernel(const int* __restrict__ labels, const float* __restrict__ eks,
                 const float* __restrict__ evs, float* __restrict__ ek,
                 float* __restrict__ ev) {
    int e = blockIdx.x * 256 + threadIdx.x;
    if (e >= SS * SS * DHD) return;
    int qk = e >> 6, d = e & 63;
    int lab = labels[qk];
    float sgn = lab > 0 ? 1.f : (lab < 0 ? -1.f : 0.f);
    ek[e] = eks[(size_t)lab * DHD + d] * sgn;
    ev[e] = evs[(size_t)lab * DHD + d] * sgn;
}

// ---------------- embedding gather + LN (eps 1e-12) -> bf16 ----------------
__global__ __launch_bounds__(256)
void embed_kernel(const int* __restrict__ ids, const float* __restrict__ emb,
                  const float* __restrict__ g, const float* __restrict__ bt,
                  bf16_t* __restrict__ out) {
    __shared__ float sred[4];
    int row = blockIdx.x;
    const float* src = emb + (size_t)ids[row] * EE;
    int c = threadIdx.x * 4;
    float4 x = *(const float4*)(src + c);
    float mean = blk_sum(x.x + x.y + x.z + x.w, sred) * (1.f / EE);
    float x0 = x.x - mean, x1 = x.y - mean, x2 = x.z - mean, x3 = x.w - mean;
    float var = blk_sum(x0*x0 + x1*x1 + x2*x2 + x3*x3, sred) * (1.f / EE);
    float rs = rsqrtf(var + 1e-12f);
    float4 gv = *(const float4*)(g + c), bv = *(const float4*)(bt + c);
    bf16x4 o;
    o[0] = (bf16_t)(x0*rs*gv.x + bv.x); o[1] = (bf16_t)(x1*rs*gv.y + bv.y);
    o[2] = (bf16_t)(x2*rs*gv.z + bv.z); o[3] = (bf16_t)(x3*rs*gv.w + bv.w);
    *(bf16x4*)(out + (size_t)row * EE + c) = o;
}

// ---------------- residual + LN (bf16 h += bf16 y, eps 1e-12) --------------
__global__ __launch_bounds__(256)
void resln_kernel(bf16_t* __restrict__ h, const bf16_t* __restrict__ y,
                  const float* __restrict__ g, const float* __restrict__ bt) {
    __shared__ float sred[4];
    int row = blockIdx.x; int c = threadIdx.x * 4;
    size_t off = (size_t)row * EE + c;
    bf16x4 a = *(const bf16x4*)(h + off), b4 = *(const bf16x4*)(y + off);
    float x0 = (float)a[0] + (float)b4[0], x1 = (float)a[1] + (float)b4[1];
    float x2 = (float)a[2] + (float)b4[2], x3 = (float)a[3] + (float)b4[3];
    float mean = blk_sum(x0 + x1 + x2 + x3, sred) * (1.f / EE);
    x0 -= mean; x1 -= mean; x2 -= mean; x3 -= mean;
    float var = blk_sum(x0*x0 + x1*x1 + x2*x2 + x3*x3, sred) * (1.f / EE);
    float rs = rsqrtf(var + 1e-12f);
    float4 gv = *(const float4*)(g + c), bv = *(const float4*)(bt + c);
    bf16x4 o;
    o[0] = (bf16_t)(x0*rs*gv.x + bv.x); o[1] = (bf16_t)(x1*rs*gv.y + bv.y);
    o[2] = (bf16_t)(x2*rs*gv.z + bv.z); o[3] = (bf16_t)(x3*rs*gv.w + bv.w);
    *(bf16x4*)(h + off) = o;
}

// ---------------- mask gather + gelu + LN (eps 1e-7) -----------------------
__global__ __launch_bounds__(256)
void hm_kernel(const bf16_t* __restrict__ h, const int* __restrict__ pos,
               const float* __restrict__ g, const float* __restrict__ bt,
               bf16_t* __restrict__ out) {
    __shared__ float sred[4];
    int b = blockIdx.x; int c = threadIdx.x * 4;
    const bf16_t* src = h + ((size_t)(b * SS + pos[b])) * EE + c;
    bf16x4 x = *(const bf16x4*)src;
    float x0 = dgelu((float)x[0]), x1 = dgelu((float)x[1]);
    float x2 = dgelu((float)x[2]), x3 = dgelu((float)x[3]);
    float mean = blk_sum(x0 + x1 + x2 + x3, sred) * (1.f / EE);
    x0 -= mean; x1 -= mean; x2 -= mean; x3 -= mean;
    float var = blk_sum(x0*x0 + x1*x1 + x2*x2 + x3*x3, sred) * (1.f / EE);
    float rs = rsqrtf(var + 1e-7f);
    float4 gv = *(const float4*)(g + c), bv = *(const float4*)(bt + c);
    bf16x4 o;
    o[0] = (bf16_t)(x0*rs*gv.x + bv.x); o[1] = (bf16_t)(x1*rs*gv.y + bv.y);
    o[2] = (bf16_t)(x2*rs*gv.z + bv.z); o[3] = (bf16_t)(x3*rs*gv.w + bv.w);
    *(bf16x4*)(out + (size_t)b * EE + c) = o;
}

// ---------------- node_emb fp32 [V][E] -> bf16 [VPAD][E] -------------------
__global__ __launch_bounds__(256)
void nodeconv_kernel(const float* __restrict__ src, bf16_t* __restrict__ dst) {
    const size_t total = (size_t)VPAD * (EE / 8);
    for (size_t idx = (size_t)blockIdx.x * 256 + threadIdx.x; idx < total;
         idx += (size_t)gridDim.x * 256) {
        size_t row = idx >> 7;
        bf16x8 o;
#pragma unroll
        for (int u = 0; u < 8; ++u) o[u] = (bf16_t)0.f;
        if (row < VV) {
            const float* s = src + (idx << 3);
            float4 a = *(const float4*)s, b = *(const float4*)(s + 4);
            o[0] = (bf16_t)a.x; o[1] = (bf16_t)a.y; o[2] = (bf16_t)a.z; o[3] = (bf16_t)a.w;
            o[4] = (bf16_t)b.x; o[5] = (bf16_t)b.y; o[6] = (bf16_t)b.z; o[7] = (bf16_t)b.w;
        }
        *(bf16x8*)(dst + (idx << 3)) = o;
    }
}

// ---------------- batched weight transpose fp32[K][N]->bf16[N][K] ----------
__global__ __launch_bounds__(256)
void transpose_kernel(const float* __restrict__ Wq, const float* __restrict__ Wk,
                      const float* __restrict__ Wv, const float* __restrict__ Wo,
                      const float* __restrict__ W1, const float* __restrict__ W2,
                      bf16_t* __restrict__ wt) {
    int t = blockIdx.x;
    const float* src; bf16_t* dst; int K, N, tile;
    if (t < 4096) {
        int mi = t >> 10; tile = t & 1023;
        src = mi == 0 ? Wq : mi == 1 ? Wk : mi == 2 ? Wv : Wo;
        dst = wt + (size_t)mi * (1u << 20);
        K = 1024; N = 1024;
    } else if (t < 8192) {
        tile = t - 4096; src = W1; dst = wt + (size_t)4 * (1u << 20); K = 1024; N = 4096;
    } else {
        tile = t - 8192; src = W2; dst = wt + (size_t)8 * (1u << 20); K = 4096; N = 1024;
    }
    int ntiles = N >> 5;
    int kt = tile / ntiles, nt = tile % ntiles;
    __shared__ float lds[32][33];
    int tx = threadIdx.x & 31, ty = threadIdx.x >> 5;
#pragma unroll
    for (int i = 0; i < 4; ++i) {
        int r = ty + i * 8;
        lds[r][tx] = src[(size_t)(kt * 32 + r) * N + nt * 32 + tx];
    }
    __syncthreads();
#pragma unroll
    for (int i = 0; i < 4; ++i) {
        int r = ty + i * 8;
        dst[(size_t)(nt * 32 + r) * K + kt * 32 + tx] = (bf16_t)lds[tx][r];
    }
}

// ---------------- GEMM 256x256, BK=32, 8 waves, counted-vmcnt prefetch -----
// EPI: 2 gelu->bf16, 4 qkv(bias seg+scale)->bf16, 0 plain->bf16
template<int EPI>
__global__ __launch_bounds__(512)
void gemm256(const bf16_t* __restrict__ A, const bf16_t* __restrict__ B,
             const float* __restrict__ b0, const float* __restrict__ b1,
             const float* __restrict__ b2, bf16_t* __restrict__ C,
             int N, int K) {
    __shared__ __align__(16) bf16_t sA[2 * 8192];
    __shared__ __align__(16) bf16_t sB[2 * 8192];
    const int tid = threadIdx.x;
    const int lane = tid & 63, wid = tid >> 6;
    const int wm = wid >> 2, wn = wid & 3;
    const int r16 = lane & 15, kb = lane >> 4;

    // bijective XCD-chunked block swizzle (m204)
    const int nwg = gridDim.x * gridDim.y;
    const int wg = blockIdx.y * gridDim.x + blockIdx.x;
    const int q8 = nwg >> 3, r8 = nwg & 7;
    const int xcd = wg & 7, loc = wg >> 3;
    const int swz = (xcd < r8 ? xcd * (q8 + 1) : r8 * (q8 + 1) + (xcd - r8) * q8) + loc;
    const int bm = swz / gridDim.x, bn = swz % gridDim.x;

    f32x4 acc[8][4];
#pragma unroll
    for (int i = 0; i < 8; ++i)
#pragma unroll
        for (int j = 0; j < 4; ++j) acc[i][j] = (f32x4){0.f, 0.f, 0.f, 0.f};

    const bf16_t* Atile = A + (size_t)bm * 256 * K;
    const bf16_t* Btile = B + (size_t)bn * 256 * K;

    // staging: tile 256x32 bf16 = 16KB = 2 calls x (8 waves x 1KB)
    // LDS(row r, 16B-slot s) holds global (r, s ^ ((r>>1)&3))   [0-conflict, proven]
    const int g_ = (lane & 3) ^ ((lane >> 3) & 3);
    const size_t soff0 = (size_t)(wid * 16 + (lane >> 2)) * K + g_ * 8;
    const size_t soff1 = soff0 + (size_t)128 * K;
    const int ldst0 = wid * 512;          // elements (wave-uniform)
    const int ldst1 = 4096 + wid * 512;

    // ds_read element offsets (constant across iterations)
    int offA[8], offB[4];
#pragma unroll
    for (int i = 0; i < 8; ++i) {
        int row = wm * 128 + i * 16 + r16;
        offA[i] = row * 32 + ((kb ^ ((row >> 1) & 3)) << 3);
    }
#pragma unroll
    for (int j = 0; j < 4; ++j) {
        int row = wn * 64 + j * 16 + r16;
        offB[j] = row * 32 + ((kb ^ ((row >> 1) & 3)) << 3);
    }

    // prologue: stage tile 0 into buf 0
    GLOAD_LDS16(Atile + soff0, sA + ldst0);
    GLOAD_LDS16(Atile + soff1, sA + ldst1);
    GLOAD_LDS16(Btile + soff0, sB + ldst0);
    GLOAD_LDS16(Btile + soff1, sB + ldst1);

    const int nt = K >> 5;
    for (int t = 0; t < nt; ++t) {
        const int cur = (t & 1) << 13;
        if (t + 1 < nt) {
            const int nxt = ((t + 1) & 1) << 13;
            const bf16_t* a_ = Atile + (size_t)(t + 1) * 32;
            const bf16_t* b_ = Btile + (size_t)(t + 1) * 32;
            GLOAD_LDS16(a_ + soff0, sA + nxt + ldst0);
            GLOAD_LDS16(a_ + soff1, sA + nxt + ldst1);
            GLOAD_LDS16(b_ + soff0, sB + nxt + ldst0);
            GLOAD_LDS16(b_ + soff1, sB + nxt + ldst1);
            asm volatile("s_waitcnt vmcnt(4)" ::: "memory");
        } else {
            asm volatile("s_waitcnt vmcnt(0)" ::: "memory");
        }
        asm volatile("s_barrier" ::: "memory");
        bf16x8 af[8], bfr[4];
#pragma unroll
        for (int i = 0; i < 8; ++i) af[i] = *(const bf16x8*)(sA + cur + offA[i]);
#pragma unroll
        for (int j = 0; j < 4; ++j) bfr[j] = *(const bf16x8*)(sB + cur + offB[j]);
        __builtin_amdgcn_s_setprio(1);
#pragma unroll
        for (int i = 0; i < 8; ++i)
#pragma unroll
            for (int j = 0; j < 4; ++j)
                acc[i][j] = __builtin_amdgcn_mfma_f32_16x16x32_bf16(af[i], bfr[j], acc[i][j], 0, 0, 0);
        __builtin_amdgcn_s_setprio(0);
        asm volatile("s_barrier" ::: "memory");
    }

    const int crow0 = bm * 256 + wm * 128;
    const int ccol0 = bn * 256 + wn * 64;
#pragma unroll
    for (int i = 0; i < 8; ++i) {
#pragma unroll
        for (int j = 0; j < 4; ++j) {
            int col = ccol0 + j * 16 + r16;
            float bias, scale = 1.f;
            if (EPI == 4) {
                int seg = col >> 10;
                const float* bp = seg == 0 ? b0 : (seg == 1 ? b1 : b2);
                bias = bp[col & 1023];
                if (seg == 0) scale = 0.125f;
            } else {
                bias = b0[col];
            }
#pragma unroll
            for (int r = 0; r < 4; ++r) {
                int rowg = crow0 + i * 16 + kb * 4 + r;
                float val = acc[i][j][r] + bias;
                if (EPI == 4) val *= scale;
                if (EPI == 2) val = fgelu(val);
                C[(size_t)rowg * N + col] = (bf16_t)val;
            }
        }
    }
}

// ---------------- GEMM 128x128 (m97 structure) ------------------------------
// EPI: 0 plain->bf16, 3 logits mask->fp32
template<int EPI, bool NB>
__global__ __launch_bounds__(256)
void gemm_bf16(const bf16_t* __restrict__ A, const bf16_t* __restrict__ B,
               const float* __restrict__ b0, const float* __restrict__ mt,
               void* __restrict__ Cout, int M, int N, int K) {
    __shared__ __align__(16) bf16_t sA[128 * 32];
    __shared__ __align__(16) bf16_t sB[128 * 32];
    const int tid = threadIdx.x;
    const int lane = tid & 63, wid = tid >> 6;
    const int wm = wid >> 1, wn = wid & 1;
    const int row16 = lane & 15, kblk = lane >> 4;

    const int nwg = gridDim.x * gridDim.y;
    const int wg = blockIdx.y * gridDim.x + blockIdx.x;
    const int q8 = nwg >> 3, r8 = nwg & 7;
    const int xcd = wg & 7, loc = wg >> 3;
    const int swz = (xcd < r8 ? xcd * (q8 + 1) : r8 * (q8 + 1) + (xcd - r8) * q8) + loc;
    const int bm = swz / gridDim.x, bn = swz % gridDim.x;

    f32x4 acc[4][4];
#pragma unroll
    for (int i = 0; i < 4; ++i)
#pragma unroll
        for (int j = 0; j < 4; ++j) acc[i][j] = (f32x4){0.f, 0.f, 0.f, 0.f};

    const bf16_t* Atile = A + (size_t)bm * 128 * K;
    const bf16_t* Btile = B + (size_t)bn * 128 * K;

    const int row_s0 = tid >> 2, chs0 = tid & 3;
    const int ch0 = chs0 ^ ((row_s0 >> 1) & 3);
    const int row_s1 = (256 + tid) >> 2, chs1 = tid & 3;
    const int ch1 = chs1 ^ ((row_s1 >> 1) & 3);
    bf16_t* ldsA0 = sA + ((size_t)(wid << 6) << 3);
    bf16_t* ldsA1 = sA + ((size_t)(256 + (wid << 6)) << 3);
    bf16_t* ldsB0 = sB + ((size_t)(wid << 6) << 3);
    bf16_t* ldsB1 = sB + ((size_t)(256 + (wid << 6)) << 3);

    for (int k0 = 0; k0 < K; k0 += 32) {
        GLOAD_LDS16(Atile + (size_t)row_s0 * K + k0 + ch0 * 8, ldsA0);
        GLOAD_LDS16(Atile + (size_t)row_s1 * K + k0 + ch1 * 8, ldsA1);
        GLOAD_LDS16(Btile + (size_t)row_s0 * K + k0 + ch0 * 8, ldsB0);
        GLOAD_LDS16(Btile + (size_t)row_s1 * K + k0 + ch1 * 8, ldsB1);
        __syncthreads();
        bf16x8 af[4], bfr[4];
#pragma unroll
        for (int i = 0; i < 4; ++i) {
            int r = wm * 64 + i * 16 + row16;
            af[i] = *(const bf16x8*)(sA + (((r << 2) | (kblk ^ ((r >> 1) & 3))) << 3));
        }
#pragma unroll
        for (int j = 0; j < 4; ++j) {
            int r = wn * 64 + j * 16 + row16;
            bfr[j] = *(const bf16x8*)(sB + (((r << 2) | (kblk ^ ((r >> 1) & 3))) << 3));
        }
#pragma unroll
        for (int i = 0; i < 4; ++i)
#pragma unroll
            for (int j = 0; j < 4; ++j)
                acc[i][j] = __builtin_amdgcn_mfma_f32_16x16x32_bf16(af[i], bfr[j], acc[i][j], 0, 0, 0);
        __syncthreads();
    }

    const int crow0 = bm * 128 + wm * 64;
    const int ccol0 = bn * 128 + wn * 64;
#pragma unroll
    for (int i = 0; i < 4; ++i) {
#pragma unroll
        for (int j = 0; j < 4; ++j) {
            int col = ccol0 + j * 16 + row16;
            if (NB && col >= N) continue;
            float bias = b0[col];
#pragma unroll
            for (int r = 0; r < 4; ++r) {
                int rowg = crow0 + i * 16 + kblk * 4 + r;
                float val = acc[i][j][r] + bias;
                if (EPI == 3) {
                    float mtb = mt[rowg];
                    float t = (col < 2) ? 0.f : fmaxf(0.f, ((col - 2) < NRELC) ? -mtb : mtb);
                    val += BIGC * (t - 1.f);
                    ((float*)Cout)[(size_t)rowg * N + col] = val;
                } else {
                    ((bf16_t*)Cout)[(size_t)rowg * N + col] = (bf16_t)val;
                }
            }
        }
    }
}

// ---------------- attention core (one block per (b,h)) ---------------------
__global__ __launch_bounds__(256)
void attn_kernel(const bf16_t* __restrict__ qkv, const float* __restrict__ ekb,
                 const float* __restrict__ evb, const float* __restrict__ mask,
                 bf16_t* __restrict__ ctx) {
    int bh = blockIdx.x; int b = bh >> 4; int h = bh & 15;
    __shared__ float sq[SS][DHD], sk[SS][DHD], sv[SS][DHD];
    __shared__ float ss[SS][SS + 1];
    __shared__ float sm[SS];
    int tid = threadIdx.x;
    for (int idx = tid; idx < 3 * SS * 8; idx += 256) {
        int t3 = idx / (SS * 8), rc = idx % (SS * 8), s = rc >> 3, c8 = rc & 7;
        bf16x8 v = *(const bf16x8*)(qkv + ((size_t)(b * SS + s)) * 3072 + t3 * 1024 + h * 64 + c8 * 8);
        float* dst = (t3 == 0 ? &sq[0][0] : t3 == 1 ? &sk[0][0] : &sv[0][0]) + s * 64 + c8 * 8;
#pragma unroll
        for (int u = 0; u < 8; ++u) dst[u] = (float)v[u];
    }
    if (tid < SS) sm[tid] = mask[b * SS + tid];
    __syncthreads();
    for (int e = tid; e < SS * SS; e += 256) {
        int qi = e / SS, ki = e % SS;
        const float* ek_ = ekb + (size_t)e * DHD;
        float acc = 0.f;
#pragma unroll 16
        for (int d = 0; d < DHD; ++d) acc += sq[qi][d] * (sk[ki][d] + ek_[d]);
        acc += BIGC * (sm[qi] * sm[ki] - 1.f);
        ss[qi][ki] = acc;
    }
    __syncthreads();
    if (tid < SS) {
        float mx = -1e30f;
        for (int ki = 0; ki < SS; ++ki) mx = fmaxf(mx, ss[tid][ki]);
        float sum = 0.f;
        for (int ki = 0; ki < SS; ++ki) { float e_ = expf(ss[tid][ki] - mx); sum += e_; ss[tid][ki] = e_; }
        float inv = 1.f / sum;
        for (int ki = 0; ki < SS; ++ki) ss[tid][ki] *= inv;
    }
    __syncthreads();
    for (int e = tid; e < SS * DHD; e += 256) {
        int qi = e >> 6, d = e & 63;
        float acc = 0.f;
#pragma unroll
        for (int ki = 0; ki < SS; ++ki)
            acc += ss[qi][ki] * (sv[ki][d] + evb[((size_t)(qi * SS + ki)) * DHD + d]);
        ctx[((size_t)(b * SS + qi)) * EE + h * DHD + d] = (bf16_t)acc;
    }
}

// ---------------- loss -----------------------------------------------------
__global__ __launch_bounds__(256)
void loss_part_kernel(const float* __restrict__ logits, const float* __restrict__ mt,
                      const int* __restrict__ label, const float* __restrict__ conf,
                      float* __restrict__ lp) {
    __shared__ float sred[4];
    int b = blockIdx.x;
    const float* row = logits + (size_t)b * VV;
    float mx = -1e30f;
    for (int j = threadIdx.x; j < VV; j += 256) mx = fmaxf(mx, row[j]);
    mx = blk_max(mx, sred);
    float m = mt[b];
    float se = 0.f, s1 = 0.f, cnt = 0.f;
    for (int j = threadIdx.x; j < VV; j += 256) {
        float x = row[j];
        se += expf(x - mx);
        float t = (j < 2) ? 0.f : fmaxf(0.f, ((j - 2) < NRELC) ? -m : m);
        s1 += t * x;
        cnt += t;
    }
    se = blk_sum(se, sred);
    s1 = blk_sum(s1, sred);
    cnt = blk_sum(cnt, sred);
    if (threadIdx.x == 0) {
        float lse = mx + logf(se);
        float lsml = row[label[b]] - lse;
        float num_cand = cnt - 1.f;
        float v = 0.9f * lsml + 0.1f * ((s1 - cnt * lse) - lsml) / num_cand;
        lp[b] = -v * conf[b];
    }
}

__global__ __launch_bounds__(256)
void loss_reduce_kernel(const float* __restrict__ lp, float* __restrict__ out) {
    __shared__ float sred[4];
    float s = 0.f;
    for (int i = threadIdx.x; i < BB; i += 256) s += lp[i];
    s = blk_sum(s, sred);
    if (threadIdx.x == 0) out[0] = s * (1.f / BB);
}

// ---------------- host ------------------------------------------------------
extern "C" void kernel_launch(void* const* d_in, const int* in_sizes, int n_in,
                              void* d_out, int out_size, void* d_ws, size_t ws_size,
                              hipStream_t stream) {
    const int*   input_ids  = (const int*)d_in[0];
    const float* input_mask = (const float*)d_in[1];
    const int*   edge_lab   = (const int*)d_in[2];
    const int*   mask_pos   = (const int*)d_in[3];
    const int*   mask_label = (const int*)d_in[4];
    const float* mask_type  = (const float*)d_in[5];
    const float* confidence = (const float*)d_in[6];
    const float* node_emb   = (const float*)d_in[7];
    const float* edge_k     = (const float*)d_in[8];
    const float* edge_v     = (const float*)d_in[9];
    const float* ln1_g      = (const float*)d_in[10];
    const float* ln1_b      = (const float*)d_in[11];
    const float* Wq         = (const float*)d_in[12];
    const float* bq         = (const float*)d_in[13];
    const float* Wk         = (const float*)d_in[14];
    const float* bk         = (const float*)d_in[15];
    const float* Wv         = (const float*)d_in[16];
    const float* bv         = (const float*)d_in[17];
    const float* Wo         = (const float*)d_in[18];
    const float* bo         = (const float*)d_in[19];
    const float* lnA_g      = (const float*)d_in[20];
    const float* lnA_b      = (const float*)d_in[21];
    const float* W1         = (const float*)d_in[22];
    const float* b1         = (const float*)d_in[23];
    const float* W2         = (const float*)d_in[24];
    const float* b2         = (const float*)d_in[25];
    const float* lnF_g      = (const float*)d_in[26];
    const float* lnF_b      = (const float*)d_in[27];
    const float* ln2_g      = (const float*)d_in[28];
    const float* ln2_b      = (const float*)d_in[29];
    const float* fc2_bias   = (const float*)d_in[30];

    char* p = (char*)d_ws;
    bf16_t* wt    = (bf16_t*)p;                                   // 24 MB
    size_t off = 25165824;
    bf16_t* hbuf  = (bf16_t*)(p + off); off += (size_t)MTOK * EE * 2;
    bf16_t* qkvb  = (bf16_t*)(p + off); off += (size_t)MTOK * FF * 2;
    bf16_t* cb    = (bf16_t*)(p + off); off += (size_t)MTOK * EE * 2;
    bf16_t* yb    = (bf16_t*)(p + off); off += (size_t)MTOK * EE * 2;
    float*  ekb   = (float*)(p + off);  off += (size_t)SS * SS * DHD * 4;
    float*  evb   = (float*)(p + off);  off += (size_t)SS * SS * DHD * 4;
    bf16_t* hmb   = (bf16_t*)(p + off); off += (size_t)BB * EE * 2;
    float*  lp    = (float*)(p + off);  off += (size_t)BB * 4;
    bf16_t* midb  = qkvb;
    bf16_t* nodeb = qkvb;

    float* loss_out   = (float*)d_out;
    float* logits_out = ((float*)d_out) + 1;

    edge_kernel<<<(SS * SS * DHD + 255) / 256, 256, 0, stream>>>(edge_lab, edge_k, edge_v, ekb, evb);
    embed_kernel<<<MTOK, 256, 0, stream>>>(input_ids, node_emb, ln1_g, ln1_b, hbuf);

    dim3 gqkv(3 * EE / 256, MTOK / 256);   // (12, 34)
    dim3 gffn1(FF / 256, MTOK / 256);      // (16, 34)
    dim3 gproj(EE / 128, MTOK / 128);      // (8, 68)

    for (int l = 0; l < LL; ++l) {
        size_t we = (size_t)l * EE * EE;
        size_t wf = (size_t)l * EE * FF;
        transpose_kernel<<<12288, 256, 0, stream>>>(Wq + we, Wk + we, Wv + we, Wo + we,
                                                    W1 + wf, W2 + wf, wt);
        gemm256<4><<<gqkv, 512, 0, stream>>>(hbuf, wt,
            bq + (size_t)l * EE, bk + (size_t)l * EE, bv + (size_t)l * EE,
            qkvb, 3 * EE, EE);
        attn_kernel<<<BB * HH, 256, 0, stream>>>(qkvb, ekb, evb, input_mask, cb);
        gemm_bf16<0, false><<<gproj, 256, 0, stream>>>(cb, wt + (size_t)3 * (1u << 20),
            bo + (size_t)l * EE, nullptr, yb, MTOK, EE, EE);
        resln_kernel<<<MTOK, 256, 0, stream>>>(hbuf, yb, lnA_g + (size_t)l * EE, lnA_b + (size_t)l * EE);
        gemm256<2><<<gffn1, 512, 0, stream>>>(hbuf, wt + (size_t)4 * (1u << 20),
            b1 + (size_t)l * FF, nullptr, nullptr, midb, FF, EE);
        gemm_bf16<0, false><<<gproj, 256, 0, stream>>>(midb, wt + (size_t)8 * (1u << 20),
            b2 + (size_t)l * EE, nullptr, yb, MTOK, EE, FF);
        resln_kernel<<<MTOK, 256, 0, stream>>>(hbuf, yb, lnF_g + (size_t)l * EE, lnF_b + (size_t)l * EE);
    }

    nodeconv_kernel<<<2048, 256, 0, stream>>>(node_emb, nodeb);
    hm_kernel<<<BB, 256, 0, stream>>>(hbuf, mask_pos, ln2_g, ln2_b, hmb);

    dim3 glog(VPAD / 128, BB / 128);   // (313, 4)
    gemm_bf16<3, true><<<glog, 256, 0, stream>>>(hmb, nodeb, fc2_bias,
        mask_type, logits_out, BB, VV, EE);

    loss_part_kernel<<<BB, 256, 0, stream>>>(logits_out, mask_type, mask_label, confidence, lp);
    loss_reduce_kernel<<<1, 256, 0, stream>>>(lp, loss_out);
}

// Round 4
// 5557.716 us; speedup vs baseline: 1.1414x; 1.1414x over previous
//
#include <hip/hip_runtime.h>
#include <hip/hip_bf16.h>

#define BB 512
#define SS 17
#define VV 40002
#define VPAD 40064
#define EE 1024
#define HH 16
#define LL 12
#define FF 4096
#define DHD 64
#define NRELC 500
#define MTOK (BB*SS)            // 8704 tokens
#define BIGC 1000000.0f

typedef __bf16 bf16_t;
typedef __bf16 bf16x8 __attribute__((ext_vector_type(8)));
typedef __bf16 bf16x4 __attribute__((ext_vector_type(4)));
typedef float  f32x4  __attribute__((ext_vector_type(4)));

#define GLOAD_LDS16(g, l) __builtin_amdgcn_global_load_lds( \
    (const __attribute__((address_space(1))) void*)(g), \
    (__attribute__((address_space(3))) void*)(l), 16, 0, 0)

__device__ __forceinline__ float dgelu(float x) {
    return 0.5f * x * (1.f + erff(x * 0.70710678118654752f));
}
// tanh-based gelu (abs err ~1e-3 — below bf16 output rounding)
__device__ __forceinline__ float fgelu(float x) {
    float y = 0.7978845608f * (x + 0.044715f * x * x * x);
    float u = __expf(2.f * y);
    float t = 1.f - 2.f / (u + 1.f);
    return 0.5f * x * (1.f + t);
}

// ---------------- block reductions (256 threads = 4 waves) ----------------
__device__ __forceinline__ float blk_sum(float v, float* sred) {
#pragma unroll
    for (int o = 32; o > 0; o >>= 1) v += __shfl_down(v, o);
    int lane = threadIdx.x & 63, w = threadIdx.x >> 6;
    __syncthreads();
    if (lane == 0) sred[w] = v;
    __syncthreads();
    return sred[0] + sred[1] + sred[2] + sred[3];
}
__device__ __forceinline__ float blk_max(float v, float* sred) {
#pragma unroll
    for (int o = 32; o > 0; o >>= 1) v = fmaxf(v, __shfl_down(v, o));
    int lane = threadIdx.x & 63, w = threadIdx.x >> 6;
    __syncthreads();
    if (lane == 0) sred[w] = v;
    __syncthreads();
    return fmaxf(fmaxf(sred[0], sred[1]), fmaxf(sred[2], sred[3]));
}

// ---------------- edge tables ----------------------------------------------
__global__ __launch_bounds__(256)
void edge_kernel(const int* __restrict__ labels, const float* __restrict__ eks,
                 const float* __restrict__ evs, float* __restrict__ ek,
                 float* __restrict__ ev) {
    int e = blockIdx.x * 256 + threadIdx.x;
    if (e >= SS * SS * DHD) return;
    int qk = e >> 6, d = e & 63;
    int lab = labels[qk];
    float sgn = lab > 0 ? 1.f : (lab < 0 ? -1.f : 0.f);
    ek[e] = eks[(size_t)lab * DHD + d] * sgn;
    ev[e] = evs[(size_t)lab * DHD + d] * sgn;
}

// ---------------- embedding gather + LN (eps 1e-12) -> bf16 ----------------
__global__ __launch_bounds__(256)
void embed_kernel(const int* __restrict__ ids, const float* __restrict__ emb,
                  const float* __restrict__ g, const float* __restrict__ bt,
                  bf16_t* __restrict__ out) {
    __shared__ float sred[4];
    int row = blockIdx.x;
    const float* src = emb + (size_t)ids[row] * EE;
    int c = threadIdx.x * 4;
    float4 x = *(const float4*)(src + c);
    float mean = blk_sum(x.x + x.y + x.z + x.w, sred) * (1.f / EE);
    float x0 = x.x - mean, x1 = x.y - mean, x2 = x.z - mean, x3 = x.w - mean;
    float var = blk_sum(x0*x0 + x1*x1 + x2*x2 + x3*x3, sred) * (1.f / EE);
    float rs = rsqrtf(var + 1e-12f);
    float4 gv = *(const float4*)(g + c), bv = *(const float4*)(bt + c);
    bf16x4 o;
    o[0] = (bf16_t)(x0*rs*gv.x + bv.x); o[1] = (bf16_t)(x1*rs*gv.y + bv.y);
    o[2] = (bf16_t)(x2*rs*gv.z + bv.z); o[3] = (bf16_t)(x3*rs*gv.w + bv.w);
    *(bf16x4*)(out + (size_t)row * EE + c) = o;
}

// ---------------- residual + LN (bf16 h += bf16 y, eps 1e-12) --------------
__global__ __launch_bounds__(256)
void resln_kernel(bf16_t* __restrict__ h, const bf16_t* __restrict__ y,
                  const float* __restrict__ g, const float* __restrict__ bt) {
    __shared__ float sred[4];
    int row = blockIdx.x; int c = threadIdx.x * 4;
    size_t off = (size_t)row * EE + c;
    bf16x4 a = *(const bf16x4*)(h + off), b4 = *(const bf16x4*)(y + off);
    float x0 = (float)a[0] + (float)b4[0], x1 = (float)a[1] + (float)b4[1];
    float x2 = (float)a[2] + (float)b4[2], x3 = (float)a[3] + (float)b4[3];
    float mean = blk_sum(x0 + x1 + x2 + x3, sred) * (1.f / EE);
    x0 -= mean; x1 -= mean; x2 -= mean; x3 -= mean;
    float var = blk_sum(x0*x0 + x1*x1 + x2*x2 + x3*x3, sred) * (1.f / EE);
    float rs = rsqrtf(var + 1e-12f);
    float4 gv = *(const float4*)(g + c), bv = *(const float4*)(bt + c);
    bf16x4 o;
    o[0] = (bf16_t)(x0*rs*gv.x + bv.x); o[1] = (bf16_t)(x1*rs*gv.y + bv.y);
    o[2] = (bf16_t)(x2*rs*gv.z + bv.z); o[3] = (bf16_t)(x3*rs*gv.w + bv.w);
    *(bf16x4*)(h + off) = o;
}

// ---------------- mask gather + gelu + LN (eps 1e-7) -----------------------
__global__ __launch_bounds__(256)
void hm_kernel(const bf16_t* __restrict__ h, const int* __restrict__ pos,
               const float* __restrict__ g, const float* __restrict__ bt,
               bf16_t* __restrict__ out) {
    __shared__ float sred[4];
    int b = blockIdx.x; int c = threadIdx.x * 4;
    const bf16_t* src = h + ((size_t)(b * SS + pos[b])) * EE + c;
    bf16x4 x = *(const bf16x4*)src;
    float x0 = dgelu((float)x[0]), x1 = dgelu((float)x[1]);
    float x2 = dgelu((float)x[2]), x3 = dgelu((float)x[3]);
    float mean = blk_sum(x0 + x1 + x2 + x3, sred) * (1.f / EE);
    x0 -= mean; x1 -= mean; x2 -= mean; x3 -= mean;
    float var = blk_sum(x0*x0 + x1*x1 + x2*x2 + x3*x3, sred) * (1.f / EE);
    float rs = rsqrtf(var + 1e-7f);
    float4 gv = *(const float4*)(g + c), bv = *(const float4*)(bt + c);
    bf16x4 o;
    o[0] = (bf16_t)(x0*rs*gv.x + bv.x); o[1] = (bf16_t)(x1*rs*gv.y + bv.y);
    o[2] = (bf16_t)(x2*rs*gv.z + bv.z); o[3] = (bf16_t)(x3*rs*gv.w + bv.w);
    *(bf16x4*)(out + (size_t)b * EE + c) = o;
}

// ---------------- node_emb fp32 [V][E] -> bf16 [VPAD][E] -------------------
__global__ __launch_bounds__(256)
void nodeconv_kernel(const float* __restrict__ src, bf16_t* __restrict__ dst) {
    const size_t total = (size_t)VPAD * (EE / 8);
    for (size_t idx = (size_t)blockIdx.x * 256 + threadIdx.x; idx < total;
         idx += (size_t)gridDim.x * 256) {
        size_t row = idx >> 7;
        bf16x8 o;
#pragma unroll
        for (int u = 0; u < 8; ++u) o[u] = (bf16_t)0.f;
        if (row < VV) {
            const float* s = src + (idx << 3);
            float4 a = *(const float4*)s, b = *(const float4*)(s + 4);
            o[0] = (bf16_t)a.x; o[1] = (bf16_t)a.y; o[2] = (bf16_t)a.z; o[3] = (bf16_t)a.w;
            o[4] = (bf16_t)b.x; o[5] = (bf16_t)b.y; o[6] = (bf16_t)b.z; o[7] = (bf16_t)b.w;
        }
        *(bf16x8*)(dst + (idx << 3)) = o;
    }
}

// ---------------- batched weight transpose fp32[K][N]->bf16[N][K] ----------
__global__ __launch_bounds__(256)
void transpose_kernel(const float* __restrict__ Wq, const float* __restrict__ Wk,
                      const float* __restrict__ Wv, const float* __restrict__ Wo,
                      const float* __restrict__ W1, const float* __restrict__ W2,
                      bf16_t* __restrict__ wt) {
    int t = blockIdx.x;
    const float* src; bf16_t* dst; int K, N, tile;
    if (t < 4096) {
        int mi = t >> 10; tile = t & 1023;
        src = mi == 0 ? Wq : mi == 1 ? Wk : mi == 2 ? Wv : Wo;
        dst = wt + (size_t)mi * (1u << 20);
        K = 1024; N = 1024;
    } else if (t < 8192) {
        tile = t - 4096; src = W1; dst = wt + (size_t)4 * (1u << 20); K = 1024; N = 4096;
    } else {
        tile = t - 8192; src = W2; dst = wt + (size_t)8 * (1u << 20); K = 4096; N = 1024;
    }
    int ntiles = N >> 5;
    int kt = tile / ntiles, nt = tile % ntiles;
    __shared__ float lds[32][33];
    int tx = threadIdx.x & 31, ty = threadIdx.x >> 5;
#pragma unroll
    for (int i = 0; i < 4; ++i) {
        int r = ty + i * 8;
        lds[r][tx] = src[(size_t)(kt * 32 + r) * N + nt * 32 + tx];
    }
    __syncthreads();
#pragma unroll
    for (int i = 0; i < 4; ++i) {
        int r = ty + i * 8;
        dst[(size_t)(nt * 32 + r) * K + kt * 32 + tx] = (bf16_t)lds[tx][r];
    }
}

// ---------------- GEMM 128x128, BK=32, 3-buffer depth-2 counted-vmcnt ------
// C[M][N] = A[M][K] x Bt[N][K] + bias. A,B bf16 via global_load_lds(16),
// slot-XOR swizzle (0 conflicts, measured). vmcnt(4) after MFMA keeps the
// t+2 prefetch in flight across the barrier; drain only in last 2 iters.
// EPI: 0 plain->bf16, 2 fgelu->bf16, 3 logits mask->fp32, 4 qkv seg-bias+scale
template<int EPI, bool NB>
__global__ __launch_bounds__(256)
void gemm_bf16(const bf16_t* __restrict__ A, const bf16_t* __restrict__ B,
               const float* __restrict__ b0, const float* __restrict__ b1,
               const float* __restrict__ b2, const float* __restrict__ mt,
               void* __restrict__ Cout, int M, int N, int K) {
    __shared__ __align__(16) bf16_t sA[3 * 4096];
    __shared__ __align__(16) bf16_t sB[3 * 4096];
    const int tid = threadIdx.x;
    const int lane = tid & 63, wid = tid >> 6;
    const int wm = wid >> 1, wn = wid & 1;
    const int row16 = lane & 15, kblk = lane >> 4;

    // bijective XCD-chunked block swizzle (m204)
    const int nwg = gridDim.x * gridDim.y;
    const int wg = blockIdx.y * gridDim.x + blockIdx.x;
    const int q8 = nwg >> 3, r8 = nwg & 7;
    const int xcd = wg & 7, loc = wg >> 3;
    const int swz = (xcd < r8 ? xcd * (q8 + 1) : r8 * (q8 + 1) + (xcd - r8) * q8) + loc;
    const int bm = swz / gridDim.x, bn = swz % gridDim.x;

    f32x4 acc[4][4];
#pragma unroll
    for (int i = 0; i < 4; ++i)
#pragma unroll
        for (int j = 0; j < 4; ++j) acc[i][j] = (f32x4){0.f, 0.f, 0.f, 0.f};

    const bf16_t* Atile = A + (size_t)bm * 128 * K;
    const bf16_t* Btile = B + (size_t)bn * 128 * K;

    // staging coords: issue0 rows 0-63 (row = tid>>2), issue1 rows 64-127.
    // LDS(row r, slot s) holds global chunk s ^ ((r>>1)&3).
    const int row_s0 = tid >> 2, chs = tid & 3;
    const int ch0 = chs ^ ((row_s0 >> 1) & 3);
    const int row_s1 = row_s0 + 64;
    const int ch1 = chs ^ ((row_s1 >> 1) & 3);
    const size_t soff0 = (size_t)row_s0 * K + ch0 * 8;
    const size_t soff1 = (size_t)row_s1 * K + ch1 * 8;
    const int ldo0 = wid * 512;           // wave-uniform LDS dst (elements)
    const int ldo1 = 2048 + wid * 512;

    // ds_read element offsets within a buffer (constant)
    int offA[4], offB[4];
#pragma unroll
    for (int i = 0; i < 4; ++i) {
        int r = wm * 64 + i * 16 + row16;
        offA[i] = r * 32 + ((kblk ^ ((r >> 1) & 3)) << 3);
    }
#pragma unroll
    for (int j = 0; j < 4; ++j) {
        int r = wn * 64 + j * 16 + row16;
        offB[j] = r * 32 + ((kblk ^ ((r >> 1) & 3)) << 3);
    }

#define STAGE_T(t_, buf_) do { \
        const bf16_t* a_ = Atile + (size_t)(t_) * 32; \
        const bf16_t* b_ = Btile + (size_t)(t_) * 32; \
        bf16_t* dA = sA + (buf_) * 4096; \
        bf16_t* dB = sB + (buf_) * 4096; \
        GLOAD_LDS16(a_ + soff0, dA + ldo0); \
        GLOAD_LDS16(a_ + soff1, dA + ldo1); \
        GLOAD_LDS16(b_ + soff0, dB + ldo0); \
        GLOAD_LDS16(b_ + soff1, dB + ldo1); \
    } while (0)

    const int nt = K >> 5;
    // prologue: prime 2 tiles
    STAGE_T(0, 0);
    STAGE_T(1, 1);
    asm volatile("s_waitcnt vmcnt(4)" ::: "memory");   // tile 0 landed
    __builtin_amdgcn_s_barrier();

    int cur = 0, stg = 2;
    for (int t = 0; t < nt; ++t) {
        const bool more = (t + 2 < nt);
        if (more) {
            STAGE_T(t + 2, stg);
            stg = (stg == 2) ? 0 : stg + 1;
        }
        const bf16_t* bufA = sA + cur * 4096;
        const bf16_t* bufB = sB + cur * 4096;
        bf16x8 af[4], bfr[4];
#pragma unroll
        for (int i = 0; i < 4; ++i) af[i] = *(const bf16x8*)(bufA + offA[i]);
#pragma unroll
        for (int j = 0; j < 4; ++j) bfr[j] = *(const bf16x8*)(bufB + offB[j]);
#pragma unroll
        for (int i = 0; i < 4; ++i)
#pragma unroll
            for (int j = 0; j < 4; ++j)
                acc[i][j] = __builtin_amdgcn_mfma_f32_16x16x32_bf16(af[i], bfr[j], acc[i][j], 0, 0, 0);
        if (t + 1 < nt) {
            if (more) asm volatile("s_waitcnt vmcnt(4)" ::: "memory"); // t+1 landed, t+2 in flight
            else      asm volatile("s_waitcnt vmcnt(0)" ::: "memory"); // tail drain
            __builtin_amdgcn_s_barrier();
        }
        cur = (cur == 2) ? 0 : cur + 1;
    }
#undef STAGE_T

    const int crow0 = bm * 128 + wm * 64;
    const int ccol0 = bn * 128 + wn * 64;
#pragma unroll
    for (int i = 0; i < 4; ++i) {
#pragma unroll
        for (int j = 0; j < 4; ++j) {
            int col = ccol0 + j * 16 + row16;
            if (NB && col >= N) continue;
            float bias, scale = 1.f;
            if (EPI == 4) {
                int seg = col >> 10;
                const float* bp = seg == 0 ? b0 : (seg == 1 ? b1 : b2);
                bias = bp[col & 1023];
                if (seg == 0) scale = 0.125f;
            } else {
                bias = b0[col];
            }
#pragma unroll
            for (int r = 0; r < 4; ++r) {
                int rowg = crow0 + i * 16 + kblk * 4 + r;
                float val = acc[i][j][r] + bias;
                if (EPI == 4) val *= scale;
                if (EPI == 2) val = fgelu(val);
                if (EPI == 3) {
                    float mtb = mt[rowg];
                    float tt = (col < 2) ? 0.f : fmaxf(0.f, ((col - 2) < NRELC) ? -mtb : mtb);
                    val += BIGC * (tt - 1.f);
                    ((float*)Cout)[(size_t)rowg * N + col] = val;
                } else {
                    ((bf16_t*)Cout)[(size_t)rowg * N + col] = (bf16_t)val;
                }
            }
        }
    }
}

// ---------------- attention core (one block per (b,h)) ---------------------
__global__ __launch_bounds__(256)
void attn_kernel(const bf16_t* __restrict__ qkv, const float* __restrict__ ekb,
                 const float* __restrict__ evb, const float* __restrict__ mask,
                 bf16_t* __restrict__ ctx) {
    int bh = blockIdx.x; int b = bh >> 4; int h = bh & 15;
    __shared__ float sq[SS][DHD], sk[SS][DHD], sv[SS][DHD];
    __shared__ float ss[SS][SS + 1];
    __shared__ float sm[SS];
    int tid = threadIdx.x;
    for (int idx = tid; idx < 3 * SS * 8; idx += 256) {
        int t3 = idx / (SS * 8), rc = idx % (SS * 8), s = rc >> 3, c8 = rc & 7;
        bf16x8 v = *(const bf16x8*)(qkv + ((size_t)(b * SS + s)) * 3072 + t3 * 1024 + h * 64 + c8 * 8);
        float* dst = (t3 == 0 ? &sq[0][0] : t3 == 1 ? &sk[0][0] : &sv[0][0]) + s * 64 + c8 * 8;
#pragma unroll
        for (int u = 0; u < 8; ++u) dst[u] = (float)v[u];
    }
    if (tid < SS) sm[tid] = mask[b * SS + tid];
    __syncthreads();
    for (int e = tid; e < SS * SS; e += 256) {
        int qi = e / SS, ki = e % SS;
        const float* ek_ = ekb + (size_t)e * DHD;
        float acc = 0.f;
#pragma unroll 16
        for (int d = 0; d < DHD; ++d) acc += sq[qi][d] * (sk[ki][d] + ek_[d]);
        acc += BIGC * (sm[qi] * sm[ki] - 1.f);
        ss[qi][ki] = acc;
    }
    __syncthreads();
    if (tid < SS) {
        float mx = -1e30f;
        for (int ki = 0; ki < SS; ++ki) mx = fmaxf(mx, ss[tid][ki]);
        float sum = 0.f;
        for (int ki = 0; ki < SS; ++ki) { float e_ = expf(ss[tid][ki] - mx); sum += e_; ss[tid][ki] = e_; }
        float inv = 1.f / sum;
        for (int ki = 0; ki < SS; ++ki) ss[tid][ki] *= inv;
    }
    __syncthreads();
    for (int e = tid; e < SS * DHD; e += 256) {
        int qi = e >> 6, d = e & 63;
        float acc = 0.f;
#pragma unroll
        for (int ki = 0; ki < SS; ++ki)
            acc += ss[qi][ki] * (sv[ki][d] + evb[((size_t)(qi * SS + ki)) * DHD + d]);
        ctx[((size_t)(b * SS + qi)) * EE + h * DHD + d] = (bf16_t)acc;
    }
}

// ---------------- loss -----------------------------------------------------
__global__ __launch_bounds__(256)
void loss_part_kernel(const float* __restrict__ logits, const float* __restrict__ mt,
                      const int* __restrict__ label, const float* __restrict__ conf,
                      float* __restrict__ lp) {
    __shared__ float sred[4];
    int b = blockIdx.x;
    const float* row = logits + (size_t)b * VV;
    float mx = -1e30f;
    for (int j = threadIdx.x; j < VV; j += 256) mx = fmaxf(mx, row[j]);
    mx = blk_max(mx, sred);
    float m = mt[b];
    float se = 0.f, s1 = 0.f, cnt = 0.f;
    for (int j = threadIdx.x; j < VV; j += 256) {
        float x = row[j];
        se += expf(x - mx);
        float t = (j < 2) ? 0.f : fmaxf(0.f, ((j - 2) < NRELC) ? -m : m);
        s1 += t * x;
        cnt += t;
    }
    se = blk_sum(se, sred);
    s1 = blk_sum(s1, sred);
    cnt = blk_sum(cnt, sred);
    if (threadIdx.x == 0) {
        float lse = mx + logf(se);
        float lsml = row[label[b]] - lse;
        float num_cand = cnt - 1.f;
        float v = 0.9f * lsml + 0.1f * ((s1 - cnt * lse) - lsml) / num_cand;
        lp[b] = -v * conf[b];
    }
}

__global__ __launch_bounds__(256)
void loss_reduce_kernel(const float* __restrict__ lp, float* __restrict__ out) {
    __shared__ float sred[4];
    float s = 0.f;
    for (int i = threadIdx.x; i < BB; i += 256) s += lp[i];
    s = blk_sum(s, sred);
    if (threadIdx.x == 0) out[0] = s * (1.f / BB);
}

// ---------------- host ------------------------------------------------------
extern "C" void kernel_launch(void* const* d_in, const int* in_sizes, int n_in,
                              void* d_out, int out_size, void* d_ws, size_t ws_size,
                              hipStream_t stream) {
    const int*   input_ids  = (const int*)d_in[0];
    const float* input_mask = (const float*)d_in[1];
    const int*   edge_lab   = (const int*)d_in[2];
    const int*   mask_pos   = (const int*)d_in[3];
    const int*   mask_label = (const int*)d_in[4];
    const float* mask_type  = (const float*)d_in[5];
    const float* confidence = (const float*)d_in[6];
    const float* node_emb   = (const float*)d_in[7];
    const float* edge_k     = (const float*)d_in[8];
    const float* edge_v     = (const float*)d_in[9];
    const float* ln1_g      = (const float*)d_in[10];
    const float* ln1_b      = (const float*)d_in[11];
    const float* Wq         = (const float*)d_in[12];
    const float* bq         = (const float*)d_in[13];
    const float* Wk         = (const float*)d_in[14];
    const float* bk         = (const float*)d_in[15];
    const float* Wv         = (const float*)d_in[16];
    const float* bv         = (const float*)d_in[17];
    const float* Wo         = (const float*)d_in[18];
    const float* bo         = (const float*)d_in[19];
    const float* lnA_g      = (const float*)d_in[20];
    const float* lnA_b      = (const float*)d_in[21];
    const float* W1         = (const float*)d_in[22];
    const float* b1         = (const float*)d_in[23];
    const float* W2         = (const float*)d_in[24];
    const float* b2         = (const float*)d_in[25];
    const float* lnF_g      = (const float*)d_in[26];
    const float* lnF_b      = (const float*)d_in[27];
    const float* ln2_g      = (const float*)d_in[28];
    const float* ln2_b      = (const float*)d_in[29];
    const float* fc2_bias   = (const float*)d_in[30];

    char* p = (char*)d_ws;
    bf16_t* wt    = (bf16_t*)p;                                   // 24 MB
    size_t off = 25165824;
    bf16_t* hbuf  = (bf16_t*)(p + off); off += (size_t)MTOK * EE * 2;
    bf16_t* qkvb  = (bf16_t*)(p + off); off += (size_t)MTOK * FF * 2;
    bf16_t* cb    = (bf16_t*)(p + off); off += (size_t)MTOK * EE * 2;
    bf16_t* yb    = (bf16_t*)(p + off); off += (size_t)MTOK * EE * 2;
    float*  ekb   = (float*)(p + off);  off += (size_t)SS * SS * DHD * 4;
    float*  evb   = (float*)(p + off);  off += (size_t)SS * SS * DHD * 4;
    bf16_t* hmb   = (bf16_t*)(p + off); off += (size_t)BB * EE * 2;
    float*  lp    = (float*)(p + off);  off += (size_t)BB * 4;
    bf16_t* midb  = qkvb;
    bf16_t* nodeb = qkvb;

    float* loss_out   = (float*)d_out;
    float* logits_out = ((float*)d_out) + 1;

    edge_kernel<<<(SS * SS * DHD + 255) / 256, 256, 0, stream>>>(edge_lab, edge_k, edge_v, ekb, evb);
    embed_kernel<<<MTOK, 256, 0, stream>>>(input_ids, node_emb, ln1_g, ln1_b, hbuf);

    dim3 gqkv(3 * EE / 128, MTOK / 128);   // (24, 68)
    dim3 gproj(EE / 128, MTOK / 128);      // (8, 68)
    dim3 gffn1(FF / 128, MTOK / 128);      // (32, 68)

    for (int l = 0; l < LL; ++l) {
        size_t we = (size_t)l * EE * EE;
        size_t wf = (size_t)l * EE * FF;
        transpose_kernel<<<12288, 256, 0, stream>>>(Wq + we, Wk + we, Wv + we, Wo + we,
                                                    W1 + wf, W2 + wf, wt);
        gemm_bf16<4, false><<<gqkv, 256, 0, stream>>>(hbuf, wt,
            bq + (size_t)l * EE, bk + (size_t)l * EE, bv + (size_t)l * EE, nullptr,
            qkvb, MTOK, 3 * EE, EE);
        attn_kernel<<<BB * HH, 256, 0, stream>>>(qkvb, ekb, evb, input_mask, cb);
        gemm_bf16<0, false><<<gproj, 256, 0, stream>>>(cb, wt + (size_t)3 * (1u << 20),
            bo + (size_t)l * EE, nullptr, nullptr, nullptr, yb, MTOK, EE, EE);
        resln_kernel<<<MTOK, 256, 0, stream>>>(hbuf, yb, lnA_g + (size_t)l * EE, lnA_b + (size_t)l * EE);
        gemm_bf16<2, false><<<gffn1, 256, 0, stream>>>(hbuf, wt + (size_t)4 * (1u << 20),
            b1 + (size_t)l * FF, nullptr, nullptr, nullptr, midb, MTOK, FF, EE);
        gemm_bf16<0, false><<<gproj, 256, 0, stream>>>(midb, wt + (size_t)8 * (1u << 20),
            b2 + (size_t)l * EE, nullptr, nullptr, nullptr, yb, MTOK, EE, FF);
        resln_kernel<<<MTOK, 256, 0, stream>>>(hbuf, yb, lnF_g + (size_t)l * EE, lnF_b + (size_t)l * EE);
    }

    nodeconv_kernel<<<2048, 256, 0, stream>>>(node_emb, nodeb);
    hm_kernel<<<BB, 256, 0, stream>>>(hbuf, mask_pos, ln2_g, ln2_b, hmb);

    dim3 glog(VPAD / 128, BB / 128);   // (313, 4)
    gemm_bf16<3, true><<<glog, 256, 0, stream>>>(hmb, nodeb, fc2_bias, nullptr, nullptr,
        mask_type, logits_out, BB, VV, EE);

    loss_part_kernel<<<BB, 256, 0, stream>>>(logits_out, mask_type, mask_label, confidence, lp);
    loss_reduce_kernel<<<1, 256, 0, stream>>>(lp, loss_out);
}

// Round 5
// 5471.052 us; speedup vs baseline: 1.1595x; 1.0158x over previous
//
#include <hip/hip_runtime.h>
#include <hip/hip_bf16.h>

#define BB 512
#define SS 17
#define VV 40002
#define VPAD 40064
#define EE 1024
#define HH 16
#define LL 12
#define FF 4096
#define DHD 64
#define NRELC 500
#define MTOK (BB*SS)            // 8704 tokens
#define BIGC 1000000.0f

typedef __bf16 bf16_t;
typedef __bf16 bf16x8 __attribute__((ext_vector_type(8)));
typedef __bf16 bf16x4 __attribute__((ext_vector_type(4)));
typedef float  f32x4  __attribute__((ext_vector_type(4)));

#define GLOAD_LDS16(g, l) __builtin_amdgcn_global_load_lds( \
    (const __attribute__((address_space(1))) void*)(g), \
    (__attribute__((address_space(3))) void*)(l), 16, 0, 0)

__device__ __forceinline__ float dgelu(float x) {
    return 0.5f * x * (1.f + erff(x * 0.70710678118654752f));
}
// tanh-based gelu (abs err ~1e-3 — below bf16 output rounding)
__device__ __forceinline__ float fgelu(float x) {
    float y = 0.7978845608f * (x + 0.044715f * x * x * x);
    float u = __expf(2.f * y);
    float t = 1.f - 2.f / (u + 1.f);
    return 0.5f * x * (1.f + t);
}

// ---------------- block reductions (256 threads = 4 waves) ----------------
__device__ __forceinline__ float blk_sum(float v, float* sred) {
#pragma unroll
    for (int o = 32; o > 0; o >>= 1) v += __shfl_down(v, o);
    int lane = threadIdx.x & 63, w = threadIdx.x >> 6;
    __syncthreads();
    if (lane == 0) sred[w] = v;
    __syncthreads();
    return sred[0] + sred[1] + sred[2] + sred[3];
}
__device__ __forceinline__ float blk_max(float v, float* sred) {
#pragma unroll
    for (int o = 32; o > 0; o >>= 1) v = fmaxf(v, __shfl_down(v, o));
    int lane = threadIdx.x & 63, w = threadIdx.x >> 6;
    __syncthreads();
    if (lane == 0) sred[w] = v;
    __syncthreads();
    return fmaxf(fmaxf(sred[0], sred[1]), fmaxf(sred[2], sred[3]));
}

// ---------------- edge tables ----------------------------------------------
__global__ __launch_bounds__(256)
void edge_kernel(const int* __restrict__ labels, const float* __restrict__ eks,
                 const float* __restrict__ evs, float* __restrict__ ek,
                 float* __restrict__ ev) {
    int e = blockIdx.x * 256 + threadIdx.x;
    if (e >= SS * SS * DHD) return;
    int qk = e >> 6, d = e & 63;
    int lab = labels[qk];
    float sgn = lab > 0 ? 1.f : (lab < 0 ? -1.f : 0.f);
    ek[e] = eks[(size_t)lab * DHD + d] * sgn;
    ev[e] = evs[(size_t)lab * DHD + d] * sgn;
}

// ---------------- embedding gather + LN (eps 1e-12) -> bf16 ----------------
__global__ __launch_bounds__(256)
void embed_kernel(const int* __restrict__ ids, const float* __restrict__ emb,
                  const float* __restrict__ g, const float* __restrict__ bt,
                  bf16_t* __restrict__ out) {
    __shared__ float sred[4];
    int row = blockIdx.x;
    const float* src = emb + (size_t)ids[row] * EE;
    int c = threadIdx.x * 4;
    float4 x = *(const float4*)(src + c);
    float mean = blk_sum(x.x + x.y + x.z + x.w, sred) * (1.f / EE);
    float x0 = x.x - mean, x1 = x.y - mean, x2 = x.z - mean, x3 = x.w - mean;
    float var = blk_sum(x0*x0 + x1*x1 + x2*x2 + x3*x3, sred) * (1.f / EE);
    float rs = rsqrtf(var + 1e-12f);
    float4 gv = *(const float4*)(g + c), bv = *(const float4*)(bt + c);
    bf16x4 o;
    o[0] = (bf16_t)(x0*rs*gv.x + bv.x); o[1] = (bf16_t)(x1*rs*gv.y + bv.y);
    o[2] = (bf16_t)(x2*rs*gv.z + bv.z); o[3] = (bf16_t)(x3*rs*gv.w + bv.w);
    *(bf16x4*)(out + (size_t)row * EE + c) = o;
}

// ---------------- residual + LN (bf16 h += bf16 y, eps 1e-12) --------------
__global__ __launch_bounds__(256)
void resln_kernel(bf16_t* __restrict__ h, const bf16_t* __restrict__ y,
                  const float* __restrict__ g, const float* __restrict__ bt) {
    __shared__ float sred[4];
    int row = blockIdx.x; int c = threadIdx.x * 4;
    size_t off = (size_t)row * EE + c;
    bf16x4 a = *(const bf16x4*)(h + off), b4 = *(const bf16x4*)(y + off);
    float x0 = (float)a[0] + (float)b4[0], x1 = (float)a[1] + (float)b4[1];
    float x2 = (float)a[2] + (float)b4[2], x3 = (float)a[3] + (float)b4[3];
    float mean = blk_sum(x0 + x1 + x2 + x3, sred) * (1.f / EE);
    x0 -= mean; x1 -= mean; x2 -= mean; x3 -= mean;
    float var = blk_sum(x0*x0 + x1*x1 + x2*x2 + x3*x3, sred) * (1.f / EE);
    float rs = rsqrtf(var + 1e-12f);
    float4 gv = *(const float4*)(g + c), bv = *(const float4*)(bt + c);
    bf16x4 o;
    o[0] = (bf16_t)(x0*rs*gv.x + bv.x); o[1] = (bf16_t)(x1*rs*gv.y + bv.y);
    o[2] = (bf16_t)(x2*rs*gv.z + bv.z); o[3] = (bf16_t)(x3*rs*gv.w + bv.w);
    *(bf16x4*)(h + off) = o;
}

// ---------------- mask gather + gelu + LN (eps 1e-7) -----------------------
__global__ __launch_bounds__(256)
void hm_kernel(const bf16_t* __restrict__ h, const int* __restrict__ pos,
               const float* __restrict__ g, const float* __restrict__ bt,
               bf16_t* __restrict__ out) {
    __shared__ float sred[4];
    int b = blockIdx.x; int c = threadIdx.x * 4;
    const bf16_t* src = h + ((size_t)(b * SS + pos[b])) * EE + c;
    bf16x4 x = *(const bf16x4*)src;
    float x0 = dgelu((float)x[0]), x1 = dgelu((float)x[1]);
    float x2 = dgelu((float)x[2]), x3 = dgelu((float)x[3]);
    float mean = blk_sum(x0 + x1 + x2 + x3, sred) * (1.f / EE);
    x0 -= mean; x1 -= mean; x2 -= mean; x3 -= mean;
    float var = blk_sum(x0*x0 + x1*x1 + x2*x2 + x3*x3, sred) * (1.f / EE);
    float rs = rsqrtf(var + 1e-7f);
    float4 gv = *(const float4*)(g + c), bv = *(const float4*)(bt + c);
    bf16x4 o;
    o[0] = (bf16_t)(x0*rs*gv.x + bv.x); o[1] = (bf16_t)(x1*rs*gv.y + bv.y);
    o[2] = (bf16_t)(x2*rs*gv.z + bv.z); o[3] = (bf16_t)(x3*rs*gv.w + bv.w);
    *(bf16x4*)(out + (size_t)b * EE + c) = o;
}

// ---------------- node_emb fp32 [V][E] -> bf16 [VPAD][E] -------------------
__global__ __launch_bounds__(256)
void nodeconv_kernel(const float* __restrict__ src, bf16_t* __restrict__ dst) {
    const size_t total = (size_t)VPAD * (EE / 8);
    for (size_t idx = (size_t)blockIdx.x * 256 + threadIdx.x; idx < total;
         idx += (size_t)gridDim.x * 256) {
        size_t row = idx >> 7;
        bf16x8 o;
#pragma unroll
        for (int u = 0; u < 8; ++u) o[u] = (bf16_t)0.f;
        if (row < VV) {
            const float* s = src + (idx << 3);
            float4 a = *(const float4*)s, b = *(const float4*)(s + 4);
            o[0] = (bf16_t)a.x; o[1] = (bf16_t)a.y; o[2] = (bf16_t)a.z; o[3] = (bf16_t)a.w;
            o[4] = (bf16_t)b.x; o[5] = (bf16_t)b.y; o[6] = (bf16_t)b.z; o[7] = (bf16_t)b.w;
        }
        *(bf16x8*)(dst + (idx << 3)) = o;
    }
}

// ---------------- batched weight transpose fp32[K][N]->bf16[N][K] ----------
__global__ __launch_bounds__(256)
void transpose_kernel(const float* __restrict__ Wq, const float* __restrict__ Wk,
                      const float* __restrict__ Wv, const float* __restrict__ Wo,
                      const float* __restrict__ W1, const float* __restrict__ W2,
                      bf16_t* __restrict__ wt) {
    int t = blockIdx.x;
    const float* src; bf16_t* dst; int K, N, tile;
    if (t < 4096) {
        int mi = t >> 10; tile = t & 1023;
        src = mi == 0 ? Wq : mi == 1 ? Wk : mi == 2 ? Wv : Wo;
        dst = wt + (size_t)mi * (1u << 20);
        K = 1024; N = 1024;
    } else if (t < 8192) {
        tile = t - 4096; src = W1; dst = wt + (size_t)4 * (1u << 20); K = 1024; N = 4096;
    } else {
        tile = t - 8192; src = W2; dst = wt + (size_t)8 * (1u << 20); K = 4096; N = 1024;
    }
    int ntiles = N >> 5;
    int kt = tile / ntiles, nt = tile % ntiles;
    __shared__ float lds[32][33];
    int tx = threadIdx.x & 31, ty = threadIdx.x >> 5;
#pragma unroll
    for (int i = 0; i < 4; ++i) {
        int r = ty + i * 8;
        lds[r][tx] = src[(size_t)(kt * 32 + r) * N + nt * 32 + tx];
    }
    __syncthreads();
#pragma unroll
    for (int i = 0; i < 4; ++i) {
        int r = ty + i * 8;
        dst[(size_t)(nt * 32 + r) * K + kt * 32 + tx] = (bf16_t)lds[tx][r];
    }
}

// ================= GEMM 256x256, BK=64, 8 waves, 4-phase counted-vmcnt =====
// Per K-tile: 4 phases (C-quadrants), per-phase 16 MFMA + ds_reads + 1-2
// half-tile stages. Steady waits vmcnt(4)/(6)/(6)/none; last tile (4)/(2)/(0).
// LDS row swizzle: 16B-slot s of row r holds global chunk s ^ (r&7).
__device__ __forceinline__ void stage_half(const bf16_t* __restrict__ gbase,
                                           bf16_t* sbase, int dstoff, int h,
                                           int t, int K, int srow, int ch, int wid) {
    const bf16_t* s0 = gbase + (size_t)(h * 128 + srow) * K + (size_t)t * 64 + ch * 8;
    const bf16_t* s1 = gbase + (size_t)(h * 128 + 64 + srow) * K + (size_t)t * 64 + ch * 8;
    GLOAD_LDS16(s0, sbase + dstoff + h * 8192 + wid * 512);
    GLOAD_LDS16(s1, sbase + dstoff + h * 8192 + 4096 + wid * 512);
}

template<bool LAST>
__device__ __forceinline__ void ktile256(
    int kt, const bf16_t* __restrict__ Atile, const bf16_t* __restrict__ Btile,
    bf16_t* sA, bf16_t* sB, int K, int srow, int ch, int wid,
    const int (&offA)[8][2], const int (&offB)[4][2], f32x4 (&acc)[8][4]) {
    const int bufo = (kt & 1) << 14;
    const int nbufo = bufo ^ (1 << 14);
    bf16x8 af[4][2], bf0[2][2], bf1[2][2];
    // ---- P1: quadrant (0,0) ----
    asm volatile("s_waitcnt vmcnt(4)" ::: "memory");
    __builtin_amdgcn_s_barrier();
#pragma unroll
    for (int i = 0; i < 4; ++i)
#pragma unroll
        for (int kk = 0; kk < 2; ++kk)
            af[i][kk] = *(const bf16x8*)(sA + bufo + offA[i][kk]);
#pragma unroll
    for (int j = 0; j < 2; ++j)
#pragma unroll
        for (int kk = 0; kk < 2; ++kk)
            bf0[j][kk] = *(const bf16x8*)(sB + bufo + offB[j][kk]);
    if (!LAST) {
        stage_half(Atile, sA, nbufo, 0, kt + 1, K, srow, ch, wid);
        stage_half(Btile, sB, nbufo, 0, kt + 1, K, srow, ch, wid);
    }
    __builtin_amdgcn_s_setprio(1);
#pragma unroll
    for (int i = 0; i < 4; ++i)
#pragma unroll
        for (int j = 0; j < 2; ++j)
#pragma unroll
            for (int kk = 0; kk < 2; ++kk)
                acc[i][j] = __builtin_amdgcn_mfma_f32_16x16x32_bf16(af[i][kk], bf0[j][kk], acc[i][j], 0, 0, 0);
    __builtin_amdgcn_s_setprio(0);
    // ---- P2: quadrant (0,1) ----
    if (LAST) asm volatile("s_waitcnt vmcnt(2)" ::: "memory");
    else      asm volatile("s_waitcnt vmcnt(6)" ::: "memory");
    __builtin_amdgcn_s_barrier();
#pragma unroll
    for (int j = 0; j < 2; ++j)
#pragma unroll
        for (int kk = 0; kk < 2; ++kk)
            bf1[j][kk] = *(const bf16x8*)(sB + bufo + offB[2 + j][kk]);
    if (!LAST) stage_half(Btile, sB, nbufo, 1, kt + 1, K, srow, ch, wid);
    __builtin_amdgcn_s_setprio(1);
#pragma unroll
    for (int i = 0; i < 4; ++i)
#pragma unroll
        for (int j = 0; j < 2; ++j)
#pragma unroll
            for (int kk = 0; kk < 2; ++kk)
                acc[i][2 + j] = __builtin_amdgcn_mfma_f32_16x16x32_bf16(af[i][kk], bf1[j][kk], acc[i][2 + j], 0, 0, 0);
    __builtin_amdgcn_s_setprio(0);
    // ---- P3: quadrant (1,1) ----
    if (LAST) asm volatile("s_waitcnt vmcnt(0)" ::: "memory");
    else      asm volatile("s_waitcnt vmcnt(6)" ::: "memory");
    __builtin_amdgcn_s_barrier();
#pragma unroll
    for (int i = 0; i < 4; ++i)
#pragma unroll
        for (int kk = 0; kk < 2; ++kk)
            af[i][kk] = *(const bf16x8*)(sA + bufo + offA[4 + i][kk]);
    if (!LAST) stage_half(Atile, sA, nbufo, 1, kt + 1, K, srow, ch, wid);
    __builtin_amdgcn_s_setprio(1);
#pragma unroll
    for (int i = 0; i < 4; ++i)
#pragma unroll
        for (int j = 0; j < 2; ++j)
#pragma unroll
            for (int kk = 0; kk < 2; ++kk)
                acc[4 + i][2 + j] = __builtin_amdgcn_mfma_f32_16x16x32_bf16(af[i][kk], bf1[j][kk], acc[4 + i][2 + j], 0, 0, 0);
    // ---- P4: quadrant (1,0), no barrier, no reads, bf0 from registers ----
#pragma unroll
    for (int i = 0; i < 4; ++i)
#pragma unroll
        for (int j = 0; j < 2; ++j)
#pragma unroll
            for (int kk = 0; kk < 2; ++kk)
                acc[4 + i][j] = __builtin_amdgcn_mfma_f32_16x16x32_bf16(af[i][kk], bf0[j][kk], acc[4 + i][j], 0, 0, 0);
    __builtin_amdgcn_s_setprio(0);
}

// EPI: 2 fgelu->bf16, 4 qkv seg-bias+scale->bf16
template<int EPI>
__global__ __launch_bounds__(512, 1)
void gemm256(const bf16_t* __restrict__ A, const bf16_t* __restrict__ B,
             const float* __restrict__ b0, const float* __restrict__ b1,
             const float* __restrict__ b2, bf16_t* __restrict__ C,
             int N, int K) {
    __shared__ __align__(16) bf16_t sA[32768];   // 2 bufs x 256 x 64
    __shared__ __align__(16) bf16_t sB[32768];
    const int tid = threadIdx.x;
    const int lane = tid & 63, wid = tid >> 6;
    const int wm = wid >> 2, wn = wid & 3;
    const int r16 = lane & 15, kblk = lane >> 4;

    const int nwg = gridDim.x * gridDim.y;
    const int wg = blockIdx.y * gridDim.x + blockIdx.x;
    const int q8 = nwg >> 3, r8 = nwg & 7;
    const int xcd = wg & 7, loc = wg >> 3;
    const int swz = (xcd < r8 ? xcd * (q8 + 1) : r8 * (q8 + 1) + (xcd - r8) * q8) + loc;
    const int bm = swz / gridDim.x, bn = swz % gridDim.x;

    f32x4 acc[8][4];
#pragma unroll
    for (int i = 0; i < 8; ++i)
#pragma unroll
        for (int j = 0; j < 4; ++j) acc[i][j] = (f32x4){0.f, 0.f, 0.f, 0.f};

    const bf16_t* Atile = A + (size_t)bm * 256 * K;
    const bf16_t* Btile = B + (size_t)bn * 256 * K;

    // staging coords: thread covers 16B chunk c (and c+512); 8 chunks/row
    const int c = wid * 64 + lane;
    const int srow = c >> 3;
    const int ch = (c & 7) ^ (srow & 7);      // inverse-swizzled global chunk

    // ds_read element offsets (slot s = chunk ^ (row&7))
    int offA[8][2], offB[4][2];
#pragma unroll
    for (int i = 0; i < 8; ++i) {
        int r = wm * 128 + i * 16 + r16;
#pragma unroll
        for (int kk = 0; kk < 2; ++kk)
            offA[i][kk] = r * 64 + (((kk * 4 + kblk) ^ (r & 7)) << 3);
    }
#pragma unroll
    for (int j = 0; j < 4; ++j) {
        int r = wn * 64 + j * 16 + r16;
#pragma unroll
        for (int kk = 0; kk < 2; ++kk)
            offB[j][kk] = r * 64 + (((kk * 4 + kblk) ^ (r & 7)) << 3);
    }

    // prologue: tile 0 (order A0,B0,B1,A1 — matches steady in-tile order)
    stage_half(Atile, sA, 0, 0, 0, K, srow, ch, wid);
    stage_half(Btile, sB, 0, 0, 0, K, srow, ch, wid);
    stage_half(Btile, sB, 0, 1, 0, K, srow, ch, wid);
    stage_half(Atile, sA, 0, 1, 0, K, srow, ch, wid);

    const int nt = K >> 6;
    for (int kt = 0; kt < nt - 1; ++kt)
        ktile256<false>(kt, Atile, Btile, sA, sB, K, srow, ch, wid, offA, offB, acc);
    ktile256<true>(nt - 1, Atile, Btile, sA, sB, K, srow, ch, wid, offA, offB, acc);

    const int crow0 = bm * 256 + wm * 128;
    const int ccol0 = bn * 256 + wn * 64;
#pragma unroll
    for (int i = 0; i < 8; ++i) {
#pragma unroll
        for (int j = 0; j < 4; ++j) {
            int col = ccol0 + j * 16 + r16;
            float bias, scale = 1.f;
            if (EPI == 4) {
                int seg = col >> 10;
                const float* bp = seg == 0 ? b0 : (seg == 1 ? b1 : b2);
                bias = bp[col & 1023];
                if (seg == 0) scale = 0.125f;
            } else {
                bias = b0[col];
            }
#pragma unroll
            for (int r = 0; r < 4; ++r) {
                int rowg = crow0 + i * 16 + kblk * 4 + r;
                float val = acc[i][j][r] + bias;
                if (EPI == 4) val *= scale;
                if (EPI == 2) val = fgelu(val);
                C[(size_t)rowg * N + col] = (bf16_t)val;
            }
        }
    }
}

// ---------------- GEMM 128x128, BK=32, 3-buffer depth-2 counted-vmcnt ------
// EPI: 0 plain->bf16, 3 logits mask->fp32
template<int EPI, bool NB>
__global__ __launch_bounds__(256)
void gemm_bf16(const bf16_t* __restrict__ A, const bf16_t* __restrict__ B,
               const float* __restrict__ b0, const float* __restrict__ mt,
               void* __restrict__ Cout, int M, int N, int K) {
    __shared__ __align__(16) bf16_t sA[3 * 4096];
    __shared__ __align__(16) bf16_t sB[3 * 4096];
    const int tid = threadIdx.x;
    const int lane = tid & 63, wid = tid >> 6;
    const int wm = wid >> 1, wn = wid & 1;
    const int row16 = lane & 15, kblk = lane >> 4;

    const int nwg = gridDim.x * gridDim.y;
    const int wg = blockIdx.y * gridDim.x + blockIdx.x;
    const int q8 = nwg >> 3, r8 = nwg & 7;
    const int xcd = wg & 7, loc = wg >> 3;
    const int swz = (xcd < r8 ? xcd * (q8 + 1) : r8 * (q8 + 1) + (xcd - r8) * q8) + loc;
    const int bm = swz / gridDim.x, bn = swz % gridDim.x;

    f32x4 acc[4][4];
#pragma unroll
    for (int i = 0; i < 4; ++i)
#pragma unroll
        for (int j = 0; j < 4; ++j) acc[i][j] = (f32x4){0.f, 0.f, 0.f, 0.f};

    const bf16_t* Atile = A + (size_t)bm * 128 * K;
    const bf16_t* Btile = B + (size_t)bn * 128 * K;

    const int row_s0 = tid >> 2, chs = tid & 3;
    const int ch0 = chs ^ ((row_s0 >> 1) & 3);
    const int row_s1 = row_s0 + 64;
    const int ch1 = chs ^ ((row_s1 >> 1) & 3);
    const size_t soff0 = (size_t)row_s0 * K + ch0 * 8;
    const size_t soff1 = (size_t)row_s1 * K + ch1 * 8;
    const int ldo0 = wid * 512;
    const int ldo1 = 2048 + wid * 512;

    int offA[4], offB[4];
#pragma unroll
    for (int i = 0; i < 4; ++i) {
        int r = wm * 64 + i * 16 + row16;
        offA[i] = r * 32 + ((kblk ^ ((r >> 1) & 3)) << 3);
    }
#pragma unroll
    for (int j = 0; j < 4; ++j) {
        int r = wn * 64 + j * 16 + row16;
        offB[j] = r * 32 + ((kblk ^ ((r >> 1) & 3)) << 3);
    }

#define STAGE_T(t_, buf_) do { \
        const bf16_t* a_ = Atile + (size_t)(t_) * 32; \
        const bf16_t* b_ = Btile + (size_t)(t_) * 32; \
        bf16_t* dA = sA + (buf_) * 4096; \
        bf16_t* dB = sB + (buf_) * 4096; \
        GLOAD_LDS16(a_ + soff0, dA + ldo0); \
        GLOAD_LDS16(a_ + soff1, dA + ldo1); \
        GLOAD_LDS16(b_ + soff0, dB + ldo0); \
        GLOAD_LDS16(b_ + soff1, dB + ldo1); \
    } while (0)

    const int nt = K >> 5;
    STAGE_T(0, 0);
    STAGE_T(1, 1);
    asm volatile("s_waitcnt vmcnt(4)" ::: "memory");
    __builtin_amdgcn_s_barrier();

    int cur = 0, stg = 2;
    for (int t = 0; t < nt; ++t) {
        const bool more = (t + 2 < nt);
        if (more) {
            STAGE_T(t + 2, stg);
            stg = (stg == 2) ? 0 : stg + 1;
        }
        const bf16_t* bufA = sA + cur * 4096;
        const bf16_t* bufB = sB + cur * 4096;
        bf16x8 af[4], bfr[4];
#pragma unroll
        for (int i = 0; i < 4; ++i) af[i] = *(const bf16x8*)(bufA + offA[i]);
#pragma unroll
        for (int j = 0; j < 4; ++j) bfr[j] = *(const bf16x8*)(bufB + offB[j]);
#pragma unroll
        for (int i = 0; i < 4; ++i)
#pragma unroll
            for (int j = 0; j < 4; ++j)
                acc[i][j] = __builtin_amdgcn_mfma_f32_16x16x32_bf16(af[i], bfr[j], acc[i][j], 0, 0, 0);
        if (t + 1 < nt) {
            if (more) asm volatile("s_waitcnt vmcnt(4)" ::: "memory");
            else      asm volatile("s_waitcnt vmcnt(0)" ::: "memory");
            __builtin_amdgcn_s_barrier();
        }
        cur = (cur == 2) ? 0 : cur + 1;
    }
#undef STAGE_T

    const int crow0 = bm * 128 + wm * 64;
    const int ccol0 = bn * 128 + wn * 64;
#pragma unroll
    for (int i = 0; i < 4; ++i) {
#pragma unroll
        for (int j = 0; j < 4; ++j) {
            int col = ccol0 + j * 16 + row16;
            if (NB && col >= N) continue;
            float bias = b0[col];
#pragma unroll
            for (int r = 0; r < 4; ++r) {
                int rowg = crow0 + i * 16 + kblk * 4 + r;
                float val = acc[i][j][r] + bias;
                if (EPI == 3) {
                    float mtb = mt[rowg];
                    float tt = (col < 2) ? 0.f : fmaxf(0.f, ((col - 2) < NRELC) ? -mtb : mtb);
                    val += BIGC * (tt - 1.f);
                    ((float*)Cout)[(size_t)rowg * N + col] = val;
                } else {
                    ((bf16_t*)Cout)[(size_t)rowg * N + col] = (bf16_t)val;
                }
            }
        }
    }
}

// ---------------- attention core (one block per (b,h)) ---------------------
__global__ __launch_bounds__(256)
void attn_kernel(const bf16_t* __restrict__ qkv, const float* __restrict__ ekb,
                 const float* __restrict__ evb, const float* __restrict__ mask,
                 bf16_t* __restrict__ ctx) {
    int bh = blockIdx.x; int b = bh >> 4; int h = bh & 15;
    __shared__ float sq[SS][DHD], sk[SS][DHD], sv[SS][DHD];
    __shared__ float ss[SS][SS + 1];
    __shared__ float sm[SS];
    int tid = threadIdx.x;
    for (int idx = tid; idx < 3 * SS * 8; idx += 256) {
        int t3 = idx / (SS * 8), rc = idx % (SS * 8), s = rc >> 3, c8 = rc & 7;
        bf16x8 v = *(const bf16x8*)(qkv + ((size_t)(b * SS + s)) * 3072 + t3 * 1024 + h * 64 + c8 * 8);
        float* dst = (t3 == 0 ? &sq[0][0] : t3 == 1 ? &sk[0][0] : &sv[0][0]) + s * 64 + c8 * 8;
#pragma unroll
        for (int u = 0; u < 8; ++u) dst[u] = (float)v[u];
    }
    if (tid < SS) sm[tid] = mask[b * SS + tid];
    __syncthreads();
    for (int e = tid; e < SS * SS; e += 256) {
        int qi = e / SS, ki = e % SS;
        const float* ek_ = ekb + (size_t)e * DHD;
        float acc = 0.f;
#pragma unroll 16
        for (int d = 0; d < DHD; ++d) acc += sq[qi][d] * (sk[ki][d] + ek_[d]);
        acc += BIGC * (sm[qi] * sm[ki] - 1.f);
        ss[qi][ki] = acc;
    }
    __syncthreads();
    if (tid < SS) {
        float mx = -1e30f;
        for (int ki = 0; ki < SS; ++ki) mx = fmaxf(mx, ss[tid][ki]);
        float sum = 0.f;
        for (int ki = 0; ki < SS; ++ki) { float e_ = expf(ss[tid][ki] - mx); sum += e_; ss[tid][ki] = e_; }
        float inv = 1.f / sum;
        for (int ki = 0; ki < SS; ++ki) ss[tid][ki] *= inv;
    }
    __syncthreads();
    for (int e = tid; e < SS * DHD; e += 256) {
        int qi = e >> 6, d = e & 63;
        float acc = 0.f;
#pragma unroll
        for (int ki = 0; ki < SS; ++ki)
            acc += ss[qi][ki] * (sv[ki][d] + evb[((size_t)(qi * SS + ki)) * DHD + d]);
        ctx[((size_t)(b * SS + qi)) * EE + h * DHD + d] = (bf16_t)acc;
    }
}

// ---------------- loss -----------------------------------------------------
__global__ __launch_bounds__(256)
void loss_part_kernel(const float* __restrict__ logits, const float* __restrict__ mt,
                      const int* __restrict__ label, const float* __restrict__ conf,
                      float* __restrict__ lp) {
    __shared__ float sred[4];
    int b = blockIdx.x;
    const float* row = logits + (size_t)b * VV;
    float mx = -1e30f;
    for (int j = threadIdx.x; j < VV; j += 256) mx = fmaxf(mx, row[j]);
    mx = blk_max(mx, sred);
    float m = mt[b];
    float se = 0.f, s1 = 0.f, cnt = 0.f;
    for (int j = threadIdx.x; j < VV; j += 256) {
        float x = row[j];
        se += expf(x - mx);
        float t = (j < 2) ? 0.f : fmaxf(0.f, ((j - 2) < NRELC) ? -m : m);
        s1 += t * x;
        cnt += t;
    }
    se = blk_sum(se, sred);
    s1 = blk_sum(s1, sred);
    cnt = blk_sum(cnt, sred);
    if (threadIdx.x == 0) {
        float lse = mx + logf(se);
        float lsml = row[label[b]] - lse;
        float num_cand = cnt - 1.f;
        float v = 0.9f * lsml + 0.1f * ((s1 - cnt * lse) - lsml) / num_cand;
        lp[b] = -v * conf[b];
    }
}

__global__ __launch_bounds__(256)
void loss_reduce_kernel(const float* __restrict__ lp, float* __restrict__ out) {
    __shared__ float sred[4];
    float s = 0.f;
    for (int i = threadIdx.x; i < BB; i += 256) s += lp[i];
    s = blk_sum(s, sred);
    if (threadIdx.x == 0) out[0] = s * (1.f / BB);
}

// ---------------- host ------------------------------------------------------
extern "C" void kernel_launch(void* const* d_in, const int* in_sizes, int n_in,
                              void* d_out, int out_size, void* d_ws, size_t ws_size,
                              hipStream_t stream) {
    const int*   input_ids  = (const int*)d_in[0];
    const float* input_mask = (const float*)d_in[1];
    const int*   edge_lab   = (const int*)d_in[2];
    const int*   mask_pos   = (const int*)d_in[3];
    const int*   mask_label = (const int*)d_in[4];
    const float* mask_type  = (const float*)d_in[5];
    const float* confidence = (const float*)d_in[6];
    const float* node_emb   = (const float*)d_in[7];
    const float* edge_k     = (const float*)d_in[8];
    const float* edge_v     = (const float*)d_in[9];
    const float* ln1_g      = (const float*)d_in[10];
    const float* ln1_b      = (const float*)d_in[11];
    const float* Wq         = (const float*)d_in[12];
    const float* bq         = (const float*)d_in[13];
    const float* Wk         = (const float*)d_in[14];
    const float* bk         = (const float*)d_in[15];
    const float* Wv         = (const float*)d_in[16];
    const float* bv         = (const float*)d_in[17];
    const float* Wo         = (const float*)d_in[18];
    const float* bo         = (const float*)d_in[19];
    const float* lnA_g      = (const float*)d_in[20];
    const float* lnA_b      = (const float*)d_in[21];
    const float* W1         = (const float*)d_in[22];
    const float* b1         = (const float*)d_in[23];
    const float* W2         = (const float*)d_in[24];
    const float* b2         = (const float*)d_in[25];
    const float* lnF_g      = (const float*)d_in[26];
    const float* lnF_b      = (const float*)d_in[27];
    const float* ln2_g      = (const float*)d_in[28];
    const float* ln2_b      = (const float*)d_in[29];
    const float* fc2_bias   = (const float*)d_in[30];

    char* p = (char*)d_ws;
    bf16_t* wt    = (bf16_t*)p;                                   // 24 MB
    size_t off = 25165824;
    bf16_t* hbuf  = (bf16_t*)(p + off); off += (size_t)MTOK * EE * 2;
    bf16_t* qkvb  = (bf16_t*)(p + off); off += (size_t)MTOK * FF * 2;
    bf16_t* cb    = (bf16_t*)(p + off); off += (size_t)MTOK * EE * 2;
    bf16_t* yb    = (bf16_t*)(p + off); off += (size_t)MTOK * EE * 2;
    float*  ekb   = (float*)(p + off);  off += (size_t)SS * SS * DHD * 4;
    float*  evb   = (float*)(p + off);  off += (size_t)SS * SS * DHD * 4;
    bf16_t* hmb   = (bf16_t*)(p + off); off += (size_t)BB * EE * 2;
    float*  lp    = (float*)(p + off);  off += (size_t)BB * 4;
    bf16_t* midb  = qkvb;
    bf16_t* nodeb = qkvb;

    float* loss_out   = (float*)d_out;
    float* logits_out = ((float*)d_out) + 1;

    edge_kernel<<<(SS * SS * DHD + 255) / 256, 256, 0, stream>>>(edge_lab, edge_k, edge_v, ekb, evb);
    embed_kernel<<<MTOK, 256, 0, stream>>>(input_ids, node_emb, ln1_g, ln1_b, hbuf);

    dim3 gqkv(3 * EE / 256, MTOK / 256);   // (12, 34)
    dim3 gffn1(FF / 256, MTOK / 256);      // (16, 34)
    dim3 gproj(EE / 128, MTOK / 128);      // (8, 68)

    for (int l = 0; l < LL; ++l) {
        size_t we = (size_t)l * EE * EE;
        size_t wf = (size_t)l * EE * FF;
        transpose_kernel<<<12288, 256, 0, stream>>>(Wq + we, Wk + we, Wv + we, Wo + we,
                                                    W1 + wf, W2 + wf, wt);
        gemm256<4><<<gqkv, 512, 0, stream>>>(hbuf, wt,
            bq + (size_t)l * EE, bk + (size_t)l * EE, bv + (size_t)l * EE,
            qkvb, 3 * EE, EE);
        attn_kernel<<<BB * HH, 256, 0, stream>>>(qkvb, ekb, evb, input_mask, cb);
        gemm_bf16<0, false><<<gproj, 256, 0, stream>>>(cb, wt + (size_t)3 * (1u << 20),
            bo + (size_t)l * EE, nullptr, yb, MTOK, EE, EE);
        resln_kernel<<<MTOK, 256, 0, stream>>>(hbuf, yb, lnA_g + (size_t)l * EE, lnA_b + (size_t)l * EE);
        gemm256<2><<<gffn1, 512, 0, stream>>>(hbuf, wt + (size_t)4 * (1u << 20),
            b1 + (size_t)l * FF, nullptr, nullptr, midb, FF, EE);
        gemm_bf16<0, false><<<gproj, 256, 0, stream>>>(midb, wt + (size_t)8 * (1u << 20),
            b2 + (size_t)l * EE, nullptr, yb, MTOK, EE, FF);
        resln_kernel<<<MTOK, 256, 0, stream>>>(hbuf, yb, lnF_g + (size_t)l * EE, lnF_b + (size_t)l * EE);
    }

    nodeconv_kernel<<<2048, 256, 0, stream>>>(node_emb, nodeb);
    hm_kernel<<<BB, 256, 0, stream>>>(hbuf, mask_pos, ln2_g, ln2_b, hmb);

    dim3 glog(VPAD / 128, BB / 128);   // (313, 4)
    gemm_bf16<3, true><<<glog, 256, 0, stream>>>(hmb, nodeb, fc2_bias,
        mask_type, logits_out, BB, VV, EE);

    loss_part_kernel<<<BB, 256, 0, stream>>>(logits_out, mask_type, mask_label, confidence, lp);
    loss_reduce_kernel<<<1, 256, 0, stream>>>(lp, loss_out);
}